// Round 3
// baseline (956.157 us; speedup 1.0000x reference)
//
#include <hip/hip_runtime.h>

#define C_EMB 256
#define NPL   9             // points per level
#define NLV   2             // levels
#define NPTS  (NPL * NLV)   // 18
#define NJ    (NPTS * 2)    // 36 offset outputs per query

__device__ __forceinline__ int imin(int a, int b) { return a < b ? a : b; }
__device__ __forceinline__ int imax(int a, int b) { return a > b ? a : b; }

// x + dpp_select(x) ; masked-out/invalid lanes contribute 0 (old=0, bound_ctrl=1)
template<int CTRL, int ROW_MASK>
__device__ __forceinline__ float dpp_add(float x) {
    int t = __builtin_amdgcn_update_dpp(0, __builtin_bit_cast(int, x),
                                        CTRL, ROW_MASK, 0xf, true);
    return x + __builtin_bit_cast(float, t);
}

// Canonical GCN wave64 sum: row_shr 1,2,4,8 then row_bcast:15 (rows 1,3),
// row_bcast:31 (rows 2,3); total lands in lane 63; broadcast via readlane.
__device__ __forceinline__ float wave_sum_all(float x) {
    x = dpp_add<0x111, 0xf>(x);   // row_shr:1
    x = dpp_add<0x112, 0xf>(x);   // row_shr:2
    x = dpp_add<0x114, 0xf>(x);   // row_shr:4
    x = dpp_add<0x118, 0xf>(x);   // row_shr:8
    x = dpp_add<0x142, 0xa>(x);   // row_bcast:15 -> rows 1,3
    x = dpp_add<0x143, 0xc>(x);   // row_bcast:31 -> rows 2,3
    int r = __builtin_amdgcn_readlane(__builtin_bit_cast(int, x), 63);
    return __builtin_bit_cast(float, r);
}

__global__ __launch_bounds__(256, 4)
void deform_attn_kernel(const float* __restrict__ query,
                        const float* __restrict__ value,
                        const float* __restrict__ refp,
                        const int*   __restrict__ sshapes,
                        const float* __restrict__ W_off,
                        const float* __restrict__ b_off,
                        float*       __restrict__ out,
                        int nq, int nv) {
    const int lane = threadIdx.x & 63;
    const int widx = threadIdx.x >> 6;
    const int q = blockIdx.x * 4 + widx;
    if (q >= nq) return;

    __shared__ int4   s_idx[4][NPTS];
    __shared__ float4 s_w[4][NPTS];

    const float* qrow = query + (size_t)q * C_EMB;

    // ---------------- offsets: lane j computes off[j] = dot(q, W[:,j]) + b[j] ----------------
    // Coalesced W reads (lanes j span 144B per c), 4 independent accumulators.
    const int jc = (lane < NJ) ? lane : (NJ - 1);
    float a0 = 0.f, a1 = 0.f, a2 = 0.f, a3 = 0.f;
    #pragma unroll 4
    for (int c = 0; c < C_EMB; c += 4) {
        float4 qv = *reinterpret_cast<const float4*>(qrow + c);
        a0 = fmaf(qv.x, W_off[(c + 0) * NJ + jc], a0);
        a1 = fmaf(qv.y, W_off[(c + 1) * NJ + jc], a1);
        a2 = fmaf(qv.z, W_off[(c + 2) * NJ + jc], a2);
        a3 = fmaf(qv.w, W_off[(c + 3) * NJ + jc], a3);
    }
    float off = (a0 + a1) + (a2 + a3) + b_off[jc];

    // partner value via quad_perm [1,0,3,2] (lane ^ 1), VALU-only
    int tsw = __builtin_amdgcn_update_dpp(0, __builtin_bit_cast(int, off),
                                          0xB1, 0xf, 0xf, true);
    float off_partner = __builtin_bit_cast(float, tsw);

    // ---------------- geometry: even lanes j=2p (p<18) ----------------
    if ((lane & 1) == 0 && lane < NJ) {
        int p = lane >> 1;
        int l = p / NPL;
        int Hi = sshapes[l * 2 + 0];
        int Wi = sshapes[l * 2 + 1];
        float fw = (float)Wi, fh = (float)Hi;
        float rx = refp[((size_t)q * NLV + l) * 2 + 0];
        float ry = refp[((size_t)q * NLV + l) * 2 + 1];
        // x = loc*W - 0.5 = ref*W + off - 0.5
        float x = rx * fw + off         - 0.5f;
        float y = ry * fh + off_partner - 0.5f;
        float x0f = floorf(x), y0f = floorf(y);
        int x0 = (int)x0f, y0 = (int)y0f;
        float wx1 = x - x0f, wy1 = y - y0f;
        float wx0 = 1.f - wx1, wy0 = 1.f - wy1;
        bool vx0 = (x0 >= 0) && (x0 <= Wi - 1);
        bool vx1 = (x0 + 1 >= 0) && (x0 + 1 <= Wi - 1);
        bool vy0 = (y0 >= 0) && (y0 <= Hi - 1);
        bool vy1 = (y0 + 1 >= 0) && (y0 + 1 <= Hi - 1);
        int cx0 = imin(imax(x0, 0), Wi - 1);
        int cx1 = imin(imax(x0 + 1, 0), Wi - 1);
        int cy0 = imin(imax(y0, 0), Hi - 1);
        int cy1 = imin(imax(y0 + 1, 0), Hi - 1);
        int base = l * nv;
        int4 id;
        id.x = base + cy0 * Wi + cx0;
        id.y = base + cy0 * Wi + cx1;
        id.z = base + cy1 * Wi + cx0;
        id.w = base + cy1 * Wi + cx1;
        float4 w;
        w.x = wx0 * wy0 * ((vx0 && vy0) ? 1.f : 0.f);
        w.y = wx1 * wy0 * ((vx1 && vy0) ? 1.f : 0.f);
        w.z = wx0 * wy1 * ((vx0 && vy1) ? 1.f : 0.f);
        w.w = wx1 * wy1 * ((vx1 && vy1) ? 1.f : 0.f);
        s_idx[widx][p] = id;
        s_w[widx][p]   = w;
    }
    __builtin_amdgcn_wave_barrier();   // wave-local LDS: same-wave DS ops are ordered

    // ---------------- pass 1: logits (no kv kept in registers) ----------------
    const int coff = lane * 4;
    const float4 q4 = *reinterpret_cast<const float4*>(qrow + coff);
    float lg[NPTS];
    #pragma unroll
    for (int p = 0; p < NPTS; ++p) {
        int4   id = s_idx[widx][p];
        float4 w  = s_w[widx][p];
        const float4 a = *reinterpret_cast<const float4*>(value + (size_t)id.x * C_EMB + coff);
        const float4 b = *reinterpret_cast<const float4*>(value + (size_t)id.y * C_EMB + coff);
        const float4 c = *reinterpret_cast<const float4*>(value + (size_t)id.z * C_EMB + coff);
        const float4 d = *reinterpret_cast<const float4*>(value + (size_t)id.w * C_EMB + coff);
        float da = q4.x * a.x + q4.y * a.y + q4.z * a.z + q4.w * a.w;
        float db = q4.x * b.x + q4.y * b.y + q4.z * b.z + q4.w * b.w;
        float dc = q4.x * c.x + q4.y * c.y + q4.z * c.z + q4.w * c.w;
        float dd = q4.x * d.x + q4.y * d.y + q4.z * d.z + q4.w * d.w;
        lg[p] = w.x * da + w.y * db + w.z * dc + w.w * dd;
    }

    // wave-reduce each logit (DPP, zero DS ops), scale by sqrt(C)=16
    #pragma unroll
    for (int p = 0; p < NPTS; ++p) lg[p] = wave_sum_all(lg[p]) * 16.0f;

    // ---------------- softmax (uniform, redundant per lane) ----------------
    float m = lg[0];
    #pragma unroll
    for (int p = 1; p < NPTS; ++p) m = fmaxf(m, lg[p]);
    float sum = 0.f;
    #pragma unroll
    for (int p = 0; p < NPTS; ++p) { lg[p] = __expf(lg[p] - m); sum += lg[p]; }
    float inv = 1.0f / sum;
    #pragma unroll
    for (int p = 0; p < NPTS; ++p) lg[p] *= inv;

    // ---------------- pass 2: re-gather (L2-hot) and accumulate output ----------------
    float4 o; o.x = 0.f; o.y = 0.f; o.z = 0.f; o.w = 0.f;
    #pragma unroll
    for (int p = 0; p < NPTS; ++p) {
        int4   id = s_idx[widx][p];
        float4 w  = s_w[widx][p];
        float ap = lg[p];
        float wa = w.x * ap, wb = w.y * ap, wc = w.z * ap, wd = w.w * ap;
        const float4 a = *reinterpret_cast<const float4*>(value + (size_t)id.x * C_EMB + coff);
        const float4 b = *reinterpret_cast<const float4*>(value + (size_t)id.y * C_EMB + coff);
        const float4 c = *reinterpret_cast<const float4*>(value + (size_t)id.z * C_EMB + coff);
        const float4 d = *reinterpret_cast<const float4*>(value + (size_t)id.w * C_EMB + coff);
        o.x += wa * a.x + wb * b.x + wc * c.x + wd * d.x;
        o.y += wa * a.y + wb * b.y + wc * c.y + wd * d.y;
        o.z += wa * a.z + wb * b.z + wc * c.z + wd * d.z;
        o.w += wa * a.w + wb * b.w + wc * c.w + wd * d.w;
    }
    *reinterpret_cast<float4*>(out + (size_t)q * C_EMB + coff) = o;
}

extern "C" void kernel_launch(void* const* d_in, const int* in_sizes, int n_in,
                              void* d_out, int out_size, void* d_ws, size_t ws_size,
                              hipStream_t stream) {
    const float* query = (const float*)d_in[0];
    // d_in[1] = key (unused by forward)
    const float* value = (const float*)d_in[2];
    const float* refp  = (const float*)d_in[3];
    const int*   ss    = (const int*)d_in[4];
    const float* W_off = (const float*)d_in[5];
    const float* b_off = (const float*)d_in[6];
    float* out = (float*)d_out;

    const int nq = in_sizes[0] / C_EMB;          // 20000
    const int nl = in_sizes[4] / 2;              // 2
    const int nv = in_sizes[2] / (nl * C_EMB);   // 16384

    const int blocks = (nq + 3) / 4;             // one wave per query, 4 waves/block
    deform_attn_kernel<<<blocks, 256, 0, stream>>>(
        query, value, refp, ss, W_off, b_off, out, nq, nv);
}

// Round 4
// 86.177 us; speedup vs baseline: 11.0953x; 11.0953x over previous
//
#include <hip/hip_runtime.h>

#define C_EMB 256
#define NPL   9             // points per level
#define NLV   2             // levels
#define NPTS  (NPL * NLV)   // 18
#define NJ    (NPTS * 2)    // 36 offset outputs per query

__global__ void transpose_woff(const float* __restrict__ W_off, float* __restrict__ WT) {
    // W_off: [C_EMB, NJ] -> WT: [NJ, C_EMB]
    int j = blockIdx.x;       // 0..35
    int c = threadIdx.x;      // 0..255
    WT[j * C_EMB + c] = W_off[c * NJ + j];
}

__device__ __forceinline__ int imin(int a, int b) { return a < b ? a : b; }
__device__ __forceinline__ int imax(int a, int b) { return a > b ? a : b; }

// x + dpp_select(x); masked-out/invalid lanes contribute 0 (old=0, bound_ctrl=1)
template<int CTRL, int ROW_MASK>
__device__ __forceinline__ float dpp_add(float x) {
    int t = __builtin_amdgcn_update_dpp(0, __builtin_bit_cast(int, x),
                                        CTRL, ROW_MASK, 0xf, true);
    return x + __builtin_bit_cast(float, t);
}

// Canonical GCN wave64 sum (VALU-only, no LDS pipe): row_shr 1,2,4,8 then
// row_bcast:15 (rows 1,3), row_bcast:31 (rows 2,3); total in lane 63,
// broadcast via readlane. HW-verified correct in round 3.
__device__ __forceinline__ float wave_sum_all(float x) {
    x = dpp_add<0x111, 0xf>(x);   // row_shr:1
    x = dpp_add<0x112, 0xf>(x);   // row_shr:2
    x = dpp_add<0x114, 0xf>(x);   // row_shr:4
    x = dpp_add<0x118, 0xf>(x);   // row_shr:8
    x = dpp_add<0x142, 0xa>(x);   // row_bcast:15 -> rows 1,3
    x = dpp_add<0x143, 0xc>(x);   // row_bcast:31 -> rows 2,3
    int r = __builtin_amdgcn_readlane(__builtin_bit_cast(int, x), 63);
    return __builtin_bit_cast(float, r);
}

template<bool USE_WT>
__global__ __launch_bounds__(256, 3)
void deform_attn_kernel(const float* __restrict__ query,
                        const float* __restrict__ value,
                        const float* __restrict__ refp,
                        const int*   __restrict__ sshapes,
                        const float* __restrict__ WT,
                        const float* __restrict__ W_off,
                        const float* __restrict__ b_off,
                        float*       __restrict__ out,
                        int nq, int nv) {
    const int lane = threadIdx.x & 63;
    const int widx = threadIdx.x >> 6;
    const int q = blockIdx.x * 4 + widx;
    if (q >= nq) return;

    __shared__ int4   s_idx[4][NPTS];
    __shared__ float4 s_w[4][NPTS];

    const float4 q4 = *reinterpret_cast<const float4*>(query + (size_t)q * C_EMB + lane * 4);

    // ---------------- sampling offsets: off[j] = dot(q, W_off[:,j]) + b_off[j] ----------------
    // DPP wave-sum makes the total uniform; lane p keeps j=2p (x) and j=2p+1 (y).
    float ox = 0.f, oy = 0.f;
    #pragma unroll
    for (int j = 0; j < NJ; ++j) {
        float s;
        if (USE_WT) {
            float4 w4 = *reinterpret_cast<const float4*>(WT + j * C_EMB + lane * 4);
            s = q4.x * w4.x + q4.y * w4.y + q4.z * w4.z + q4.w * w4.w;
        } else {
            const float* wp = W_off + (lane * 4) * NJ + j;
            s = q4.x * wp[0] + q4.y * wp[NJ] + q4.z * wp[2 * NJ] + q4.w * wp[3 * NJ];
        }
        s = wave_sum_all(s) + b_off[j];
        if (j == 2 * lane)     ox = s;
        if (j == 2 * lane + 1) oy = s;
    }

    // ---------------- geometry: lanes 0..17 each handle one (level, point) ----------------
    if (lane < NPTS) {
        int l = lane / NPL;
        int Hi = sshapes[l * 2 + 0];
        int Wi = sshapes[l * 2 + 1];
        float fw = (float)Wi, fh = (float)Hi;
        float rx = refp[((size_t)q * NLV + l) * 2 + 0];
        float ry = refp[((size_t)q * NLV + l) * 2 + 1];
        // x = (2*loc-1 + 1)*W/2 - 0.5 = loc*W - 0.5 ; loc = ref + off/W  -> x = ref*W + off - 0.5
        float x = rx * fw + ox - 0.5f;
        float y = ry * fh + oy - 0.5f;
        float x0f = floorf(x), y0f = floorf(y);
        int x0 = (int)x0f, y0 = (int)y0f;
        float wx1 = x - x0f, wy1 = y - y0f;
        float wx0 = 1.f - wx1, wy0 = 1.f - wy1;
        bool vx0 = (x0 >= 0) && (x0 <= Wi - 1);
        bool vx1 = (x0 + 1 >= 0) && (x0 + 1 <= Wi - 1);
        bool vy0 = (y0 >= 0) && (y0 <= Hi - 1);
        bool vy1 = (y0 + 1 >= 0) && (y0 + 1 <= Hi - 1);
        int cx0 = imin(imax(x0, 0), Wi - 1);
        int cx1 = imin(imax(x0 + 1, 0), Wi - 1);
        int cy0 = imin(imax(y0, 0), Hi - 1);
        int cy1 = imin(imax(y0 + 1, 0), Hi - 1);
        int base = l * nv;
        int4 id;
        id.x = base + cy0 * Wi + cx0;
        id.y = base + cy0 * Wi + cx1;
        id.z = base + cy1 * Wi + cx0;
        id.w = base + cy1 * Wi + cx1;
        float4 w;
        w.x = wx0 * wy0 * ((vx0 && vy0) ? 1.f : 0.f);
        w.y = wx1 * wy0 * ((vx1 && vy0) ? 1.f : 0.f);
        w.z = wx0 * wy1 * ((vx0 && vy1) ? 1.f : 0.f);
        w.w = wx1 * wy1 * ((vx1 && vy1) ? 1.f : 0.f);
        s_idx[widx][lane] = id;
        s_w[widx][lane]   = w;
    }
    __builtin_amdgcn_wave_barrier();   // wave-local LDS producer->consumer; ds ops are wave-ordered

    // ---------------- bilinear sampling + per-lane logit partials (single pass, kv in regs) ----
    const int coff = lane * 4;
    float4 kv[NPTS];
    float  lg[NPTS];
    #pragma unroll
    for (int p = 0; p < NPTS; ++p) {
        int4   id = s_idx[widx][p];
        float4 w  = s_w[widx][p];
        const float4 a = *reinterpret_cast<const float4*>(value + (size_t)id.x * C_EMB + coff);
        const float4 b = *reinterpret_cast<const float4*>(value + (size_t)id.y * C_EMB + coff);
        const float4 c = *reinterpret_cast<const float4*>(value + (size_t)id.z * C_EMB + coff);
        const float4 d = *reinterpret_cast<const float4*>(value + (size_t)id.w * C_EMB + coff);
        float4 acc;
        acc.x = w.x * a.x + w.y * b.x + w.z * c.x + w.w * d.x;
        acc.y = w.x * a.y + w.y * b.y + w.z * c.y + w.w * d.y;
        acc.z = w.x * a.z + w.y * b.z + w.z * c.z + w.w * d.z;
        acc.w = w.x * a.w + w.y * b.w + w.z * c.w + w.w * d.w;
        kv[p] = acc;
        lg[p] = q4.x * acc.x + q4.y * acc.y + q4.z * acc.z + q4.w * acc.w;
    }

    // ---------------- reduce logits across the wave (DPP, all lanes get totals) ----------------
    #pragma unroll
    for (int p = 0; p < NPTS; ++p) {
        lg[p] = wave_sum_all(lg[p]) * 16.0f;   // * sqrt(C), C=256
    }

    // ---------------- softmax (uniform, redundant per lane) + weighted sum ----------------
    float m = lg[0];
    #pragma unroll
    for (int p = 1; p < NPTS; ++p) m = fmaxf(m, lg[p]);
    float sum = 0.f;
    #pragma unroll
    for (int p = 0; p < NPTS; ++p) { lg[p] = __expf(lg[p] - m); sum += lg[p]; }
    float inv = 1.0f / sum;

    float4 o; o.x = 0.f; o.y = 0.f; o.z = 0.f; o.w = 0.f;
    #pragma unroll
    for (int p = 0; p < NPTS; ++p) {
        o.x += lg[p] * kv[p].x;
        o.y += lg[p] * kv[p].y;
        o.z += lg[p] * kv[p].z;
        o.w += lg[p] * kv[p].w;
    }
    o.x *= inv; o.y *= inv; o.z *= inv; o.w *= inv;
    *reinterpret_cast<float4*>(out + (size_t)q * C_EMB + coff) = o;
}

extern "C" void kernel_launch(void* const* d_in, const int* in_sizes, int n_in,
                              void* d_out, int out_size, void* d_ws, size_t ws_size,
                              hipStream_t stream) {
    const float* query = (const float*)d_in[0];
    // d_in[1] = key (unused by forward)
    const float* value = (const float*)d_in[2];
    const float* refp  = (const float*)d_in[3];
    const int*   ss    = (const int*)d_in[4];
    const float* W_off = (const float*)d_in[5];
    const float* b_off = (const float*)d_in[6];
    float* out = (float*)d_out;

    const int nq = in_sizes[0] / C_EMB;          // 20000
    const int nl = in_sizes[4] / 2;              // 2
    const int nv = in_sizes[2] / (nl * C_EMB);   // 16384

    const int blocks = (nq + 3) / 4;             // one wave per query, 4 waves/block

    const size_t wt_bytes = (size_t)NJ * C_EMB * sizeof(float);
    if (ws_size >= wt_bytes) {
        float* WT = (float*)d_ws;
        transpose_woff<<<NJ, C_EMB, 0, stream>>>(W_off, WT);
        deform_attn_kernel<true><<<blocks, 256, 0, stream>>>(
            query, value, refp, ss, WT, W_off, b_off, out, nq, nv);
    } else {
        deform_attn_kernel<false><<<blocks, 256, 0, stream>>>(
            query, value, refp, ss, nullptr, W_off, b_off, out, nq, nv);
    }
}

// Round 5
// 84.368 us; speedup vs baseline: 11.3331x; 1.0214x over previous
//
#include <hip/hip_runtime.h>

#define C_EMB 256
#define NPL   9             // points per level
#define NLV   2             // levels
#define NPTS  (NPL * NLV)   // 18
#define NJ    (NPTS * 2)    // 36 offset outputs per query

__global__ void transpose_woff(const float* __restrict__ W_off, float* __restrict__ WT) {
    // W_off: [C_EMB, NJ] -> WT: [NJ, C_EMB]
    int j = blockIdx.x;       // 0..35
    int c = threadIdx.x;      // 0..255
    WT[j * C_EMB + c] = W_off[c * NJ + j];
}

__device__ __forceinline__ int imin(int a, int b) { return a < b ? a : b; }
__device__ __forceinline__ int imax(int a, int b) { return a > b ? a : b; }

// x + dpp_select(x); masked-out/invalid lanes contribute 0 (old=0, bound_ctrl=1)
template<int CTRL, int ROW_MASK>
__device__ __forceinline__ float dpp_add(float x) {
    int t = __builtin_amdgcn_update_dpp(0, __builtin_bit_cast(int, x),
                                        CTRL, ROW_MASK, 0xf, true);
    return x + __builtin_bit_cast(float, t);
}

// Canonical GCN wave64 sum (VALU-only, no LDS pipe): row_shr 1,2,4,8 then
// row_bcast:15 (rows 1,3), row_bcast:31 (rows 2,3); total in lane 63,
// broadcast via readlane. HW-verified correct (rounds 3-4).
__device__ __forceinline__ float wave_sum_all(float x) {
    x = dpp_add<0x111, 0xf>(x);   // row_shr:1
    x = dpp_add<0x112, 0xf>(x);   // row_shr:2
    x = dpp_add<0x114, 0xf>(x);   // row_shr:4
    x = dpp_add<0x118, 0xf>(x);   // row_shr:8
    x = dpp_add<0x142, 0xa>(x);   // row_bcast:15 -> rows 1,3
    x = dpp_add<0x143, 0xc>(x);   // row_bcast:31 -> rows 2,3
    int r = __builtin_amdgcn_readlane(__builtin_bit_cast(int, x), 63);
    return __builtin_bit_cast(float, r);
}

template<bool USE_WT>
__global__ __launch_bounds__(256)   // R5: no waves-per-eu attr -> let occupancy float
void deform_attn_kernel(const float* __restrict__ query,
                        const float* __restrict__ value,
                        const float* __restrict__ refp,
                        const int*   __restrict__ sshapes,
                        const float* __restrict__ WT,
                        const float* __restrict__ W_off,
                        const float* __restrict__ b_off,
                        float*       __restrict__ out,
                        int nq, int nv) {
    const int lane = threadIdx.x & 63;
    const int widx = threadIdx.x >> 6;
    const int q = blockIdx.x * 4 + widx;
    if (q >= nq) return;

    __shared__ int4   s_idx[4][NPTS];
    __shared__ float4 s_w[4][NPTS];

    const float4 q4 = *reinterpret_cast<const float4*>(query + (size_t)q * C_EMB + lane * 4);

    // ---------------- sampling offsets: off[j] = dot(q, W_off[:,j]) + b_off[j] ----------------
    // DPP wave-sum makes the total uniform; lane p keeps j=2p (x) and j=2p+1 (y).
    float ox = 0.f, oy = 0.f;
    #pragma unroll
    for (int j = 0; j < NJ; ++j) {
        float s;
        if (USE_WT) {
            float4 w4 = *reinterpret_cast<const float4*>(WT + j * C_EMB + lane * 4);
            s = q4.x * w4.x + q4.y * w4.y + q4.z * w4.z + q4.w * w4.w;
        } else {
            const float* wp = W_off + (lane * 4) * NJ + j;
            s = q4.x * wp[0] + q4.y * wp[NJ] + q4.z * wp[2 * NJ] + q4.w * wp[3 * NJ];
        }
        s = wave_sum_all(s) + b_off[j];
        if (j == 2 * lane)     ox = s;
        if (j == 2 * lane + 1) oy = s;
    }

    // ---------------- geometry: lanes 0..17 each handle one (level, point) ----------------
    if (lane < NPTS) {
        int l = lane / NPL;
        int Hi = sshapes[l * 2 + 0];
        int Wi = sshapes[l * 2 + 1];
        float fw = (float)Wi, fh = (float)Hi;
        float rx = refp[((size_t)q * NLV + l) * 2 + 0];
        float ry = refp[((size_t)q * NLV + l) * 2 + 1];
        // x = (2*loc-1 + 1)*W/2 - 0.5 = loc*W - 0.5 ; loc = ref + off/W  -> x = ref*W + off - 0.5
        float x = rx * fw + ox - 0.5f;
        float y = ry * fh + oy - 0.5f;
        float x0f = floorf(x), y0f = floorf(y);
        int x0 = (int)x0f, y0 = (int)y0f;
        float wx1 = x - x0f, wy1 = y - y0f;
        float wx0 = 1.f - wx1, wy0 = 1.f - wy1;
        bool vx0 = (x0 >= 0) && (x0 <= Wi - 1);
        bool vx1 = (x0 + 1 >= 0) && (x0 + 1 <= Wi - 1);
        bool vy0 = (y0 >= 0) && (y0 <= Hi - 1);
        bool vy1 = (y0 + 1 >= 0) && (y0 + 1 <= Hi - 1);
        int cx0 = imin(imax(x0, 0), Wi - 1);
        int cx1 = imin(imax(x0 + 1, 0), Wi - 1);
        int cy0 = imin(imax(y0, 0), Hi - 1);
        int cy1 = imin(imax(y0 + 1, 0), Hi - 1);
        int base = l * nv;
        int4 id;
        id.x = base + cy0 * Wi + cx0;
        id.y = base + cy0 * Wi + cx1;
        id.z = base + cy1 * Wi + cx0;
        id.w = base + cy1 * Wi + cx1;
        float4 w;
        w.x = wx0 * wy0 * ((vx0 && vy0) ? 1.f : 0.f);
        w.y = wx1 * wy0 * ((vx1 && vy0) ? 1.f : 0.f);
        w.z = wx0 * wy1 * ((vx0 && vy1) ? 1.f : 0.f);
        w.w = wx1 * wy1 * ((vx1 && vy1) ? 1.f : 0.f);
        s_idx[widx][lane] = id;
        s_w[widx][lane]   = w;
    }
    __builtin_amdgcn_wave_barrier();   // wave-local LDS producer->consumer; ds ops are wave-ordered

    // ---------------- bilinear sampling + per-lane logit partials (single pass, kv in regs) ----
    const int coff = lane * 4;
    float4 kv[NPTS];
    float  lg[NPTS];
    #pragma unroll
    for (int p = 0; p < NPTS; ++p) {
        int4   id = s_idx[widx][p];
        float4 w  = s_w[widx][p];
        const float4 a = *reinterpret_cast<const float4*>(value + (size_t)id.x * C_EMB + coff);
        const float4 b = *reinterpret_cast<const float4*>(value + (size_t)id.y * C_EMB + coff);
        const float4 c = *reinterpret_cast<const float4*>(value + (size_t)id.z * C_EMB + coff);
        const float4 d = *reinterpret_cast<const float4*>(value + (size_t)id.w * C_EMB + coff);
        float4 acc;
        acc.x = w.x * a.x + w.y * b.x + w.z * c.x + w.w * d.x;
        acc.y = w.x * a.y + w.y * b.y + w.z * c.y + w.w * d.y;
        acc.z = w.x * a.z + w.y * b.z + w.z * c.z + w.w * d.z;
        acc.w = w.x * a.w + w.y * b.w + w.z * c.w + w.w * d.w;
        kv[p] = acc;
        lg[p] = q4.x * acc.x + q4.y * acc.y + q4.z * acc.z + q4.w * acc.w;
    }

    // ---------------- reduce logits across the wave (DPP, all lanes get totals) ----------------
    #pragma unroll
    for (int p = 0; p < NPTS; ++p) {
        lg[p] = wave_sum_all(lg[p]) * 16.0f;   // * sqrt(C), C=256
    }

    // ---------------- softmax (uniform, redundant per lane) + weighted sum ----------------
    float m = lg[0];
    #pragma unroll
    for (int p = 1; p < NPTS; ++p) m = fmaxf(m, lg[p]);
    float sum = 0.f;
    #pragma unroll
    for (int p = 0; p < NPTS; ++p) { lg[p] = __expf(lg[p] - m); sum += lg[p]; }
    float inv = 1.0f / sum;

    float4 o; o.x = 0.f; o.y = 0.f; o.z = 0.f; o.w = 0.f;
    #pragma unroll
    for (int p = 0; p < NPTS; ++p) {
        o.x += lg[p] * kv[p].x;
        o.y += lg[p] * kv[p].y;
        o.z += lg[p] * kv[p].z;
        o.w += lg[p] * kv[p].w;
    }
    o.x *= inv; o.y *= inv; o.z *= inv; o.w *= inv;
    *reinterpret_cast<float4*>(out + (size_t)q * C_EMB + coff) = o;
}

extern "C" void kernel_launch(void* const* d_in, const int* in_sizes, int n_in,
                              void* d_out, int out_size, void* d_ws, size_t ws_size,
                              hipStream_t stream) {
    const float* query = (const float*)d_in[0];
    // d_in[1] = key (unused by forward)
    const float* value = (const float*)d_in[2];
    const float* refp  = (const float*)d_in[3];
    const int*   ss    = (const int*)d_in[4];
    const float* W_off = (const float*)d_in[5];
    const float* b_off = (const float*)d_in[6];
    float* out = (float*)d_out;

    const int nq = in_sizes[0] / C_EMB;          // 20000
    const int nl = in_sizes[4] / 2;              // 2
    const int nv = in_sizes[2] / (nl * C_EMB);   // 16384

    const int blocks = (nq + 3) / 4;             // one wave per query, 4 waves/block

    const size_t wt_bytes = (size_t)NJ * C_EMB * sizeof(float);
    if (ws_size >= wt_bytes) {
        float* WT = (float*)d_ws;
        transpose_woff<<<NJ, C_EMB, 0, stream>>>(W_off, WT);
        deform_attn_kernel<true><<<blocks, 256, 0, stream>>>(
            query, value, refp, ss, WT, W_off, b_off, out, nq, nv);
    } else {
        deform_attn_kernel<false><<<blocks, 256, 0, stream>>>(
            query, value, refp, ss, nullptr, W_off, b_off, out, nq, nv);
    }
}